// Round 1
// baseline (97.264 us; speedup 1.0000x reference)
//
#include <hip/hip_runtime.h>
#include <math.h>

// LDDMM variational RHS, Gaussian kernel sigma=0.1, B=1, N=8192, D=3.
// out[0:N*3]       = dmom_i = (1/sig^2) * (x_i * sum_j W_ij - sum_j W_ij x_j)
// out[N*3:2*N*3]   = dcp_i  = sum_j K_ij p_j
// K_ij = exp(-|x_i-x_j|^2 / (2 sig^2)),  W_ij = K_ij * (p_i . p_j),
// p = clamp(mom, -1, 1).
//
// Strategy: all-pairs, j-dimension split across blocks for CU saturation
// (32 i-blocks alone would use only 32/256 CUs). Partials are linear in
// (wsum, wx, dcp) so each (i, j-chunk) contribution is atomicAdd'ed into
// d_out, which is zeroed by hipMemsetAsync at the top of kernel_launch.

#define NPTS 8192
#define BI   256          // threads per block == i's per block
#define JC   32           // number of j-chunks
#define JLEN (NPTS / JC)  // 256 j's per chunk

// exp(-d2/(2*0.1^2)) = exp2(d2 * (-50 * log2(e)))
#define EXP2_COEF (-72.134752044448170f)

__device__ __forceinline__ float fast_exp2(float x) {
#if __has_builtin(__builtin_amdgcn_exp2f)
    return __builtin_amdgcn_exp2f(x);
#else
    return exp2f(x);
#endif
}

__device__ __forceinline__ float clamp1(float v) {
    return fminf(fmaxf(v, -1.0f), 1.0f);
}

__global__ __launch_bounds__(BI) void lddmm_pairs(const float* __restrict__ mom,
                                                  const float* __restrict__ cp,
                                                  float* __restrict__ out) {
    const int ib = (int)blockIdx.x / JC;   // i-block
    const int jc = (int)blockIdx.x % JC;   // j-chunk
    const int t  = (int)threadIdx.x;
    const int i  = ib * BI + t;

    // Per-thread i data
    const float xi0 = cp[i * 3 + 0];
    const float xi1 = cp[i * 3 + 1];
    const float xi2 = cp[i * 3 + 2];
    const float pi0 = clamp1(mom[i * 3 + 0]);
    const float pi1 = clamp1(mom[i * 3 + 1]);
    const float pi2 = clamp1(mom[i * 3 + 2]);

    // Stage this block's j-chunk into LDS (float4 for ds_read_b128)
    __shared__ float4 shx[JLEN];
    __shared__ float4 shp[JLEN];
    {
        const int j = jc * JLEN + t;
        shx[t] = make_float4(cp[j * 3 + 0], cp[j * 3 + 1], cp[j * 3 + 2], 0.0f);
        shp[t] = make_float4(clamp1(mom[j * 3 + 0]), clamp1(mom[j * 3 + 1]),
                             clamp1(mom[j * 3 + 2]), 0.0f);
    }
    __syncthreads();

    float dcp0 = 0.f, dcp1 = 0.f, dcp2 = 0.f;
    float wsum = 0.f;
    float wx0 = 0.f, wx1 = 0.f, wx2 = 0.f;

#pragma unroll 4
    for (int jj = 0; jj < JLEN; ++jj) {
        const float4 xj = shx[jj];   // wave-uniform address -> LDS broadcast
        const float4 pj = shp[jj];
        const float dx0 = xi0 - xj.x;
        const float dx1 = xi1 - xj.y;
        const float dx2 = xi2 - xj.z;
        const float d2  = dx0 * dx0 + dx1 * dx1 + dx2 * dx2;
        const float K   = fast_exp2(d2 * EXP2_COEF);
        const float pd  = pi0 * pj.x + pi1 * pj.y + pi2 * pj.z;
        const float W   = K * pd;
        dcp0 += K * pj.x;
        dcp1 += K * pj.y;
        dcp2 += K * pj.z;
        wsum += W;
        wx0 += W * xj.x;
        wx1 += W * xj.y;
        wx2 += W * xj.z;
    }

    // dmom contribution of this chunk (linear in wsum/wx): 100 = 1/sig^2
    const float dm0 = 100.0f * (xi0 * wsum - wx0);
    const float dm1 = 100.0f * (xi1 * wsum - wx1);
    const float dm2 = 100.0f * (xi2 * wsum - wx2);

    atomicAdd(&out[i * 3 + 0], dm0);
    atomicAdd(&out[i * 3 + 1], dm1);
    atomicAdd(&out[i * 3 + 2], dm2);
    atomicAdd(&out[NPTS * 3 + i * 3 + 0], dcp0);
    atomicAdd(&out[NPTS * 3 + i * 3 + 1], dcp1);
    atomicAdd(&out[NPTS * 3 + i * 3 + 2], dcp2);
}

extern "C" void kernel_launch(void* const* d_in, const int* in_sizes, int n_in,
                              void* d_out, int out_size, void* d_ws, size_t ws_size,
                              hipStream_t stream) {
    const float* mom = (const float*)d_in[0];
    const float* cp  = (const float*)d_in[1];
    float* out = (float*)d_out;

    // d_out is poisoned 0xAA before every launch; we accumulate atomically.
    hipMemsetAsync(out, 0, (size_t)out_size * sizeof(float), stream);

    dim3 grid(NPTS / BI * JC);  // 32 i-blocks x 32 j-chunks = 1024 blocks
    dim3 block(BI);
    hipLaunchKernelGGL(lddmm_pairs, grid, block, 0, stream, mom, cp, out);
}